// Round 5
// baseline (1982.822 us; speedup 1.0000x reference)
//
#include <hip/hip_runtime.h>
#include <stdint.h>

#define N_NODES 50000
#define M_PAD   50048   // 391*128
#define NIN     512
#define HDIM    512
#define DDIM    128
#define A_ADJ   3
#define E_EDGES 800000
#define BKTS    391     // buckets per adjacency, 128 rows each (391*128 = 50048)
#define CAP     2560    // slots per bucket: lambda=2048, +11 sigma headroom

typedef __bf16 bf16x8 __attribute__((ext_vector_type(8)));
typedef float  f32x4  __attribute__((ext_vector_type(4)));

// ---------------- JAX threefry2x32 (bit-exact, partitionable mode) ----------------
__host__ __device__ inline void tf_round(uint32_t& x0, uint32_t& x1, int r) {
  x0 += x1; x1 = (x1 << r) | (x1 >> (32 - r)); x1 ^= x0;
}
__host__ __device__ inline void threefry2x32(uint32_t k0, uint32_t k1,
                                             uint32_t x0, uint32_t x1,
                                             uint32_t& o0, uint32_t& o1) {
  uint32_t ks2 = k0 ^ k1 ^ 0x1BD11BDAu;
  x0 += k0; x1 += k1;
  tf_round(x0,x1,13); tf_round(x0,x1,15); tf_round(x0,x1,26); tf_round(x0,x1,6);
  x0 += k1; x1 += ks2 + 1u;
  tf_round(x0,x1,17); tf_round(x0,x1,29); tf_round(x0,x1,16); tf_round(x0,x1,24);
  x0 += ks2; x1 += k0 + 2u;
  tf_round(x0,x1,13); tf_round(x0,x1,15); tf_round(x0,x1,26); tf_round(x0,x1,6);
  x0 += k0; x1 += k1 + 3u;
  tf_round(x0,x1,17); tf_round(x0,x1,29); tf_round(x0,x1,16); tf_round(x0,x1,24);
  x0 += k1; x1 += ks2 + 4u;
  tf_round(x0,x1,13); tf_round(x0,x1,15); tf_round(x0,x1,26); tf_round(x0,x1,6);
  x0 += ks2; x1 += k0 + 5u;
  o0 = x0; o1 = x1;
}

__device__ inline bool keep_bit(uint32_t b) {
  float f = __uint_as_float((b >> 9) | 0x3f800000u) - 1.0f;
  return f < 0.8f;
}
__device__ inline uint16_t f2bf(float f) {           // RNE float->bf16
  uint32_t u = __float_as_uint(f);
  return (uint16_t)((u + 0x7fffu + ((u >> 16) & 1u)) >> 16);
}
__device__ inline float bf2f(uint16_t b) { return __uint_as_float(((uint32_t)b) << 16); }

__device__ inline uint32_t rbits32(uint32_t ka, uint32_t kb, uint32_t i) {
  uint32_t o0, o1;
  threefry2x32(ka, kb, 0u, i, o0, o1);
  return o0 ^ o1;
}

// ---------------- input dropout: seq_a (f32) -> x (bf16) ----------------
__global__ void k_dropin(const float* __restrict__ seq, uint16_t* __restrict__ x,
                         uint32_t ka, uint32_t kb) {
  const int TOT4 = (N_NODES * NIN) / 4;
  int t = blockIdx.x * blockDim.x + threadIdx.x;
  if (t >= TOT4) return;
  int i0 = 4 * t;
  float4 v = ((const float4*)seq)[t];
  float f[4] = {v.x, v.y, v.z, v.w};
  uint16_t r[4];
#pragma unroll
  for (int j = 0; j < 4; ++j) {
    uint32_t bits = rbits32(ka, kb, (uint32_t)(i0 + j));
    r[j] = f2bf(keep_bit(bits) ? f[j] * 1.25f : 0.0f);
  }
  uint2 w;
  w.x = (uint32_t)r[0] | ((uint32_t)r[1] << 16);
  w.y = (uint32_t)r[2] | ((uint32_t)r[3] << 16);
  ((uint2*)x)[t] = w;
}

// ---------------- h_a dropout: h_a (f32, d_out) -> hp0 (bf16) ----------------
__global__ void k_drop2(const float* __restrict__ ha, uint16_t* __restrict__ hp0,
                        uint32_t ka, uint32_t kb) {
  const int TOT4 = (N_NODES * DDIM) / 4;
  int t = blockIdx.x * blockDim.x + threadIdx.x;
  if (t >= TOT4) return;
  int i0 = 4 * t;
  float4 v = ((const float4*)ha)[t];
  float f[4] = {v.x, v.y, v.z, v.w};
  uint16_t r[4];
#pragma unroll
  for (int j = 0; j < 4; ++j) {
    uint32_t bits = rbits32(ka, kb, (uint32_t)(i0 + j));
    r[j] = f2bf(keep_bit(bits) ? f[j] * 1.25f : 0.0f);
  }
  uint2 w;
  w.x = (uint32_t)r[0] | ((uint32_t)r[1] << 16);
  w.y = (uint32_t)r[2] | ((uint32_t)r[3] << 16);
  ((uint2*)hp0)[t] = w;
}

// ---------------- weight transpose + bf16 convert ----------------
__global__ void k_transpose(const float* __restrict__ W, uint16_t* __restrict__ Wt,
                            int R, int C) {
  int t = blockIdx.x * blockDim.x + threadIdx.x;
  if (t >= (R * C) / 2) return;
  int k2 = (2 * t) % R;
  int n  = (2 * t) / R;
  uint32_t p = (uint32_t)f2bf(W[(size_t)k2 * C + n])
             | ((uint32_t)f2bf(W[(size_t)(k2 + 1) * C + n]) << 16);
  *(uint32_t*)&Wt[(size_t)n * R + k2] = p;
}

// ---------------- GEMM (unchanged) ----------------
template <int MODE>
__global__ __launch_bounds__(256) void k_gemm(const uint16_t* __restrict__ A,
                                              const uint16_t* __restrict__ Bt,
                                              const float* __restrict__ bias,
                                              uint16_t* __restrict__ hOut,
                                              float* __restrict__ fOut,
                                              int Nn, int K) {
  __shared__ __align__(16) uint16_t As[128 * 32];
  __shared__ __align__(16) uint16_t Bs[128 * 32];
  const int t  = threadIdx.x;
  const int w  = t >> 6, l = t & 63;
  const int lm = l & 15, kg = l >> 4;
  const int wr = w >> 1, wc = w & 1;
  const int rowbase = blockIdx.y * 128;
  const int colbase = blockIdx.x * 128;
  const int c0 = t, c1 = t + 256;

  f32x4 acc[4][4] = {};

  for (int kt = 0; kt < K; kt += 32) {
    uint4 va0 = *(const uint4*)&A [(size_t)(rowbase + (c0 >> 2)) * K + kt + (c0 & 3) * 8];
    uint4 va1 = *(const uint4*)&A [(size_t)(rowbase + (c1 >> 2)) * K + kt + (c1 & 3) * 8];
    uint4 vb0 = *(const uint4*)&Bt[(size_t)(colbase + (c0 >> 2)) * K + kt + (c0 & 3) * 8];
    uint4 vb1 = *(const uint4*)&Bt[(size_t)(colbase + (c1 >> 2)) * K + kt + (c1 & 3) * 8];
    __syncthreads();
    *(uint4*)&As[c0 * 8] = va0;
    *(uint4*)&As[c1 * 8] = va1;
    *(uint4*)&Bs[c0 * 8] = vb0;
    *(uint4*)&Bs[c1 * 8] = vb1;
    __syncthreads();

    bf16x8 af[4], bfr[4];
#pragma unroll
    for (int m = 0; m < 4; ++m)
      af[m] = *(const bf16x8*)&As[(wr * 64 + m * 16 + lm) * 32 + kg * 8];
#pragma unroll
    for (int n = 0; n < 4; ++n)
      bfr[n] = *(const bf16x8*)&Bs[(wc * 64 + n * 16 + lm) * 32 + kg * 8];
#pragma unroll
    for (int m = 0; m < 4; ++m)
#pragma unroll
      for (int n = 0; n < 4; ++n)
        acc[m][n] = __builtin_amdgcn_mfma_f32_16x16x32_bf16(af[m], bfr[n], acc[m][n], 0, 0, 0);
  }

#pragma unroll
  for (int m = 0; m < 4; ++m) {
    int r0 = rowbase + wr * 64 + m * 16 + kg * 4;
#pragma unroll
    for (int n = 0; n < 4; ++n) {
      int cc = colbase + wc * 64 + n * 16 + lm;
      float bv = bias[cc];
#pragma unroll
      for (int r = 0; r < 4; ++r) {
        int row = r0 + r;
        if (row < N_NODES) {
          float v = acc[m][n][r] + bv;
          if (MODE == 0) hOut[(size_t)row * Nn + cc] = f2bf(fmaxf(v, 0.0f));
          else           fOut[(size_t)row * Nn + cc] = v;
        }
      }
    }
  }
}

// ---------------- bucket scatter: fixed-capacity buckets of 128 rows ----------------
// Writes are bucket-cursor-sequential -> L2 merges lines (low write amplification).
__global__ void k_scatter_bkt(const int* __restrict__ rows, const int* __restrict__ cols,
                              const float* __restrict__ vals, uint32_t* __restrict__ bcur,
                              uint64_t* __restrict__ sedge) {
  int t = blockIdx.x * blockDim.x + threadIdx.x;      // over A*E
  if (t >= A_ADJ * E_EDGES) return;
  int a = t / E_EDGES;
  uint32_t row = (uint32_t)rows[t];
  uint32_t bkt = (uint32_t)a * BKTS + (row >> 7);
  uint32_t pos = atomicAdd(&bcur[bkt << 4], 1u);      // cursor padded to 64B line
  if (pos >= CAP) return;                              // ~11-sigma guard, never taken
  uint64_t packed = ((uint64_t)__float_as_uint(vals[t]) << 32)
                  | ((row & 127u) << 16) | (uint32_t)cols[t];   // col < 50000 < 2^16
  sedge[(size_t)bkt * CAP + pos] = packed;
}

// ---------------- SpMM: one block per bucket, LDS f32 accumulation ----------------
__global__ __launch_bounds__(512) void k_spmm_lds(const uint32_t* __restrict__ bcur,
                                                  const uint64_t* __restrict__ sedge,
                                                  const uint16_t* __restrict__ hp0,
                                                  float* __restrict__ stack) {
  __shared__ float acc[128 * 128];                    // 64 KB: [rowLocal][dim]
  const int blk = blockIdx.x;                         // a*BKTS + b
  const int tid = threadIdx.x;
  float4* accf4 = (float4*)acc;
#pragma unroll
  for (int i = 0; i < 8; ++i) accf4[tid + i * 512] = make_float4(0.f, 0.f, 0.f, 0.f);
  __syncthreads();

  uint32_t cnt = bcur[blk << 4];
  if (cnt > CAP) cnt = CAP;
  const uint64_t* eb = sedge + (size_t)blk * CAP;
  const uint32_t* hp32 = (const uint32_t*)hp0;
  const int wv = tid >> 6, l = tid & 63;

  uint32_t i = wv;
  for (; i + 8 < cnt; i += 16) {                      // 2-deep unroll (waves stride 8)
    uint64_t e0 = eb[i], e1 = eb[i + 8];
    uint32_t lo0 = (uint32_t)e0, lo1 = (uint32_t)e1;
    uint32_t p0 = hp32[(size_t)(lo0 & 0xffffu) * 64 + l];
    uint32_t p1 = hp32[(size_t)(lo1 & 0xffffu) * 64 + l];
    float v0 = __uint_as_float((uint32_t)(e0 >> 32));
    float v1 = __uint_as_float((uint32_t)(e1 >> 32));
    uint32_t r0 = (lo0 >> 16) & 127u, r1 = (lo1 >> 16) & 127u;
    atomicAdd(&acc[r0 * 128 + 2 * l],     bf2f((uint16_t)(p0 & 0xffffu)) * v0);
    atomicAdd(&acc[r0 * 128 + 2 * l + 1], bf2f((uint16_t)(p0 >> 16)) * v0);
    atomicAdd(&acc[r1 * 128 + 2 * l],     bf2f((uint16_t)(p1 & 0xffffu)) * v1);
    atomicAdd(&acc[r1 * 128 + 2 * l + 1], bf2f((uint16_t)(p1 >> 16)) * v1);
  }
  for (; i < cnt; i += 8) {
    uint64_t e0 = eb[i];
    uint32_t lo0 = (uint32_t)e0;
    uint32_t p0 = hp32[(size_t)(lo0 & 0xffffu) * 64 + l];
    float v0 = __uint_as_float((uint32_t)(e0 >> 32));
    uint32_t r0 = (lo0 >> 16) & 127u;
    atomicAdd(&acc[r0 * 128 + 2 * l],     bf2f((uint16_t)(p0 & 0xffffu)) * v0);
    atomicAdd(&acc[r0 * 128 + 2 * l + 1], bf2f((uint16_t)(p0 >> 16)) * v0);
  }
  __syncthreads();

  // flush: 128 rows x 512B, coalesced; skip pad rows (>= N_NODES)
  const int a = blk / BKTS, b = blk % BKTS;
  const int row0 = b * 128;
  const size_t basef4 = ((size_t)a * N_NODES + row0) << 5;   // f4 units (32 per row)
#pragma unroll
  for (int k = 0; k < 8; ++k) {
    int q = tid + k * 512;                             // f4 index in tile (4096 total)
    int r = q >> 5;
    if (row0 + r < N_NODES)
      ((float4*)stack)[basef4 + q] = accf4[q];
  }
}

// ---------------- fusion: mean over A ----------------
__global__ void k_fusion(const float* __restrict__ stack, float* __restrict__ fus) {
  const int Q = (N_NODES * DDIM) / 4;
  int t = blockIdx.x * blockDim.x + threadIdx.x;
  if (t >= Q) return;
  const float4* s = (const float4*)stack;
  float4 s0 = s[t], s1 = s[t + Q], s2 = s[t + 2 * Q];
  float4 r;
  r.x = (s0.x + s1.x + s2.x) * (1.0f / 3.0f);
  r.y = (s0.y + s1.y + s2.y) * (1.0f / 3.0f);
  r.z = (s0.z + s1.z + s2.z) * (1.0f / 3.0f);
  r.w = (s0.w + s1.w + s2.w) * (1.0f / 3.0f);
  ((float4*)fus)[t] = r;
}

extern "C" void kernel_launch(void* const* d_in, const int* in_sizes, int n_in,
                              void* d_out, int out_size, void* d_ws, size_t ws_size,
                              hipStream_t stream) {
  const float* seq  = (const float*)d_in[0];
  const float* W1   = (const float*)d_in[1];
  const float* b1   = (const float*)d_in[2];
  const float* W2   = (const float*)d_in[3];
  const float* b2   = (const float*)d_in[4];
  const float* vals = (const float*)d_in[5];
  const int*   rows = (const int*)d_in[6];
  const int*   cols = (const int*)d_in[7];

  float* out       = (float*)d_out;
  float* out_ha    = out;                                       // [N, D]
  float* out_stack = out + (size_t)N_NODES * DDIM;              // [A, N, D]
  float* out_fus   = out_stack + (size_t)A_ADJ * N_NODES * DDIM;

  uint16_t* x   = (uint16_t*)d_ws;                              // [M_PAD, NIN] bf16 (51.2MB)
  uint16_t* h   = x   + (size_t)M_PAD * NIN;                    // [M_PAD, HDIM] bf16
  uint16_t* w1t = h   + (size_t)M_PAD * HDIM;                   // [HDIM, NIN]  bf16
  uint16_t* w2t = w1t + (size_t)HDIM * NIN;                     // [DDIM, HDIM] bf16
  uint16_t* hp0 = w2t + (size_t)DDIM * HDIM;                    // [N, D] bf16

  // bucket buffers alias the x region (x dead after k_gemm<0>)
  char* xbase = (char*)d_ws;
  uint64_t* sedge = (uint64_t*)(xbase);                         // [A*BKTS*CAP] 24MB
  uint32_t* bcur  = (uint32_t*)(xbase + 25 * 1024 * 1024);      // [A*BKTS*16] 75KB padded

  // JAX partitionable-mode split of key (0,42)
  uint32_t k0a, k0b, k1a, k1b;
  threefry2x32(0u, 42u, 0u, 0u, k0a, k0b);
  threefry2x32(0u, 42u, 0u, 1u, k1a, k1b);

  k_transpose<<<(HDIM * NIN / 2 + 255) / 256, 256, 0, stream>>>(W1, w1t, NIN, HDIM);
  k_transpose<<<(HDIM * DDIM / 2 + 255) / 256, 256, 0, stream>>>(W2, w2t, HDIM, DDIM);

  k_dropin<<<((N_NODES * NIN / 4) + 255) / 256, 256, 0, stream>>>(seq, x, k0a, k0b);

  dim3 g1(HDIM / 128, M_PAD / 128);   // (4, 391)
  k_gemm<0><<<g1, 256, 0, stream>>>(x, w1t, b1, h, nullptr, HDIM, NIN);

  // ---- bucket scatter (x region now dead) ----
  (void)hipMemsetAsync(bcur, 0, (size_t)A_ADJ * BKTS * 16 * sizeof(uint32_t), stream);
  k_scatter_bkt<<<(A_ADJ * E_EDGES + 255) / 256, 256, 0, stream>>>(rows, cols, vals, bcur, sedge);

  dim3 g2(DDIM / 128, M_PAD / 128);   // (1, 391)
  k_gemm<1><<<g2, 256, 0, stream>>>(h, w2t, b2, nullptr, out_ha, DDIM, HDIM);

  k_drop2<<<((N_NODES * DDIM / 4) + 255) / 256, 256, 0, stream>>>(out_ha, hp0, k1a, k1b);

  k_spmm_lds<<<A_ADJ * BKTS, 512, 0, stream>>>(bcur, sedge, hp0, out_stack);

  k_fusion<<<((N_NODES * DDIM / 4) + 255) / 256, 256, 0, stream>>>(out_stack, out_fus);
}

// Round 6
// 383.148 us; speedup vs baseline: 5.1751x; 5.1751x over previous
//
#include <hip/hip_runtime.h>
#include <stdint.h>

#define N_NODES 50000
#define M_PAD   50048   // 391*128
#define NIN     512
#define HDIM    512
#define DDIM    128
#define A_ADJ   3
#define E_EDGES 800000
#define TOT_E   (A_ADJ * E_EDGES)           // 2,400,000
#define TOT_ROWS (A_ADJ * N_NODES)          // 150,000
#define CB      49                          // coarse bins per adjacency (1024 rows each)
#define NB      (A_ADJ * CB)                // 147
#define CHUNK   2048
#define NCHB    ((TOT_E + CHUNK - 1) / CHUNK)   // 1172

typedef __bf16 bf16x8 __attribute__((ext_vector_type(8)));
typedef float  f32x4  __attribute__((ext_vector_type(4)));

// ---------------- JAX threefry2x32 (bit-exact, partitionable mode) ----------------
__host__ __device__ inline void tf_round(uint32_t& x0, uint32_t& x1, int r) {
  x0 += x1; x1 = (x1 << r) | (x1 >> (32 - r)); x1 ^= x0;
}
__host__ __device__ inline void threefry2x32(uint32_t k0, uint32_t k1,
                                             uint32_t x0, uint32_t x1,
                                             uint32_t& o0, uint32_t& o1) {
  uint32_t ks2 = k0 ^ k1 ^ 0x1BD11BDAu;
  x0 += k0; x1 += k1;
  tf_round(x0,x1,13); tf_round(x0,x1,15); tf_round(x0,x1,26); tf_round(x0,x1,6);
  x0 += k1; x1 += ks2 + 1u;
  tf_round(x0,x1,17); tf_round(x0,x1,29); tf_round(x0,x1,16); tf_round(x0,x1,24);
  x0 += ks2; x1 += k0 + 2u;
  tf_round(x0,x1,13); tf_round(x0,x1,15); tf_round(x0,x1,26); tf_round(x0,x1,6);
  x0 += k0; x1 += k1 + 3u;
  tf_round(x0,x1,17); tf_round(x0,x1,29); tf_round(x0,x1,16); tf_round(x0,x1,24);
  x0 += k1; x1 += ks2 + 4u;
  tf_round(x0,x1,13); tf_round(x0,x1,15); tf_round(x0,x1,26); tf_round(x0,x1,6);
  x0 += ks2; x1 += k0 + 5u;
  o0 = x0; o1 = x1;
}

__device__ inline bool keep_bit(uint32_t b) {
  float f = __uint_as_float((b >> 9) | 0x3f800000u) - 1.0f;
  return f < 0.8f;
}
__device__ inline uint16_t f2bf(float f) {           // RNE float->bf16
  uint32_t u = __float_as_uint(f);
  return (uint16_t)((u + 0x7fffu + ((u >> 16) & 1u)) >> 16);
}
__device__ inline float bf2f(uint16_t b) { return __uint_as_float(((uint32_t)b) << 16); }

__device__ inline uint32_t rbits32(uint32_t ka, uint32_t kb, uint32_t i) {
  uint32_t o0, o1;
  threefry2x32(ka, kb, 0u, i, o0, o1);
  return o0 ^ o1;
}

// ---------------- input dropout: seq_a (f32) -> x (bf16) ----------------
__global__ void k_dropin(const float* __restrict__ seq, uint16_t* __restrict__ x,
                         uint32_t ka, uint32_t kb) {
  const int TOT4 = (N_NODES * NIN) / 4;
  int t = blockIdx.x * blockDim.x + threadIdx.x;
  if (t >= TOT4) return;
  int i0 = 4 * t;
  float4 v = ((const float4*)seq)[t];
  float f[4] = {v.x, v.y, v.z, v.w};
  uint16_t r[4];
#pragma unroll
  for (int j = 0; j < 4; ++j) {
    uint32_t bits = rbits32(ka, kb, (uint32_t)(i0 + j));
    r[j] = f2bf(keep_bit(bits) ? f[j] * 1.25f : 0.0f);
  }
  uint2 w;
  w.x = (uint32_t)r[0] | ((uint32_t)r[1] << 16);
  w.y = (uint32_t)r[2] | ((uint32_t)r[3] << 16);
  ((uint2*)x)[t] = w;
}

// ---------------- h_a dropout: h_a (f32, d_out) -> hp0 (bf16) ----------------
__global__ void k_drop2(const float* __restrict__ ha, uint16_t* __restrict__ hp0,
                        uint32_t ka, uint32_t kb) {
  const int TOT4 = (N_NODES * DDIM) / 4;
  int t = blockIdx.x * blockDim.x + threadIdx.x;
  if (t >= TOT4) return;
  int i0 = 4 * t;
  float4 v = ((const float4*)ha)[t];
  float f[4] = {v.x, v.y, v.z, v.w};
  uint16_t r[4];
#pragma unroll
  for (int j = 0; j < 4; ++j) {
    uint32_t bits = rbits32(ka, kb, (uint32_t)(i0 + j));
    r[j] = f2bf(keep_bit(bits) ? f[j] * 1.25f : 0.0f);
  }
  uint2 w;
  w.x = (uint32_t)r[0] | ((uint32_t)r[1] << 16);
  w.y = (uint32_t)r[2] | ((uint32_t)r[3] << 16);
  ((uint2*)hp0)[t] = w;
}

// ---------------- weight transpose + bf16 convert ----------------
__global__ void k_transpose(const float* __restrict__ W, uint16_t* __restrict__ Wt,
                            int R, int C) {
  int t = blockIdx.x * blockDim.x + threadIdx.x;
  if (t >= (R * C) / 2) return;
  int k2 = (2 * t) % R;
  int n  = (2 * t) / R;
  uint32_t p = (uint32_t)f2bf(W[(size_t)k2 * C + n])
             | ((uint32_t)f2bf(W[(size_t)(k2 + 1) * C + n]) << 16);
  *(uint32_t*)&Wt[(size_t)n * R + k2] = p;
}

// ---------------- GEMM (round-4, unchanged) ----------------
template <int MODE>
__global__ __launch_bounds__(256) void k_gemm(const uint16_t* __restrict__ A,
                                              const uint16_t* __restrict__ Bt,
                                              const float* __restrict__ bias,
                                              uint16_t* __restrict__ hOut,
                                              float* __restrict__ fOut,
                                              int Nn, int K) {
  __shared__ __align__(16) uint16_t As[128 * 32];
  __shared__ __align__(16) uint16_t Bs[128 * 32];
  const int t  = threadIdx.x;
  const int w  = t >> 6, l = t & 63;
  const int lm = l & 15, kg = l >> 4;
  const int wr = w >> 1, wc = w & 1;
  const int rowbase = blockIdx.y * 128;
  const int colbase = blockIdx.x * 128;
  const int c0 = t, c1 = t + 256;

  f32x4 acc[4][4] = {};

  for (int kt = 0; kt < K; kt += 32) {
    uint4 va0 = *(const uint4*)&A [(size_t)(rowbase + (c0 >> 2)) * K + kt + (c0 & 3) * 8];
    uint4 va1 = *(const uint4*)&A [(size_t)(rowbase + (c1 >> 2)) * K + kt + (c1 & 3) * 8];
    uint4 vb0 = *(const uint4*)&Bt[(size_t)(colbase + (c0 >> 2)) * K + kt + (c0 & 3) * 8];
    uint4 vb1 = *(const uint4*)&Bt[(size_t)(colbase + (c1 >> 2)) * K + kt + (c1 & 3) * 8];
    __syncthreads();
    *(uint4*)&As[c0 * 8] = va0;
    *(uint4*)&As[c1 * 8] = va1;
    *(uint4*)&Bs[c0 * 8] = vb0;
    *(uint4*)&Bs[c1 * 8] = vb1;
    __syncthreads();

    bf16x8 af[4], bfr[4];
#pragma unroll
    for (int m = 0; m < 4; ++m)
      af[m] = *(const bf16x8*)&As[(wr * 64 + m * 16 + lm) * 32 + kg * 8];
#pragma unroll
    for (int n = 0; n < 4; ++n)
      bfr[n] = *(const bf16x8*)&Bs[(wc * 64 + n * 16 + lm) * 32 + kg * 8];
#pragma unroll
    for (int m = 0; m < 4; ++m)
#pragma unroll
      for (int n = 0; n < 4; ++n)
        acc[m][n] = __builtin_amdgcn_mfma_f32_16x16x32_bf16(af[m], bfr[n], acc[m][n], 0, 0, 0);
  }

#pragma unroll
  for (int m = 0; m < 4; ++m) {
    int r0 = rowbase + wr * 64 + m * 16 + kg * 4;
#pragma unroll
    for (int n = 0; n < 4; ++n) {
      int cc = colbase + wc * 64 + n * 16 + lm;
      float bv = bias[cc];
#pragma unroll
      for (int r = 0; r < 4; ++r) {
        int row = r0 + r;
        if (row < N_NODES) {
          float v = acc[m][n][r] + bv;
          if (MODE == 0) hOut[(size_t)row * Nn + cc] = f2bf(fmaxf(v, 0.0f));
          else           fOut[(size_t)row * Nn + cc] = v;
        }
      }
    }
  }
}

// ---------------- coarse histogram: 147 bins, LDS-staged ----------------
__global__ __launch_bounds__(256) void k_bhist(const int* __restrict__ rows,
                                               uint32_t* __restrict__ gh) {
  __shared__ uint32_t h[NB];
  const int tid = threadIdx.x;
  if (tid < NB) h[tid] = 0;
  __syncthreads();
  const int cb = blockIdx.x * CHUNK;
  const int cnt = min(CHUNK, TOT_E - cb);
  for (int c = tid; c < cnt; c += 256) {
    int e = cb + c;
    int a = e / E_EDGES;
    uint32_t r = (uint32_t)rows[e];
    atomicAdd(&h[a * CB + (r >> 10)], 1u);
  }
  __syncthreads();
  if (tid < NB && h[tid]) atomicAdd(&gh[tid], h[tid]);
}

// ---------------- coarse scan: 147 bins -> bases & cursors ----------------
__global__ __launch_bounds__(256) void k_bscan(const uint32_t* __restrict__ gh,
                                               uint32_t* __restrict__ gbase,
                                               uint32_t* __restrict__ gcur,
                                               uint32_t* __restrict__ offs) {
  __shared__ uint32_t s[256];
  const int tid = threadIdx.x;
  uint32_t v = (tid < NB) ? gh[tid] : 0u;
  s[tid] = v;
  __syncthreads();
  for (int off = 1; off < 256; off <<= 1) {
    uint32_t w = (tid >= off) ? s[tid - off] : 0u;
    __syncthreads();
    s[tid] += w;
    __syncthreads();
  }
  if (tid < NB) { uint32_t excl = s[tid] - v; gbase[tid] = excl; gcur[tid] = excl; }
  if (tid == NB - 1) gbase[NB] = s[tid];
  if (tid == 0) offs[TOT_ROWS] = (uint32_t)TOT_E;
}

// ---------------- pass 1: chunk-sort 2048 edges into coarse-bin runs ----------------
// Each block's writes per bin are contiguous runs (~14 edges) -> L2 line merge.
__global__ __launch_bounds__(256) void k_pass1(const int* __restrict__ rows,
                                               const int* __restrict__ cols,
                                               const float* __restrict__ vals,
                                               uint32_t* __restrict__ gcur,
                                               uint64_t* __restrict__ sedgeA) {
  __shared__ __align__(16) uint64_t lbuf[CHUNK];      // 16 KB
  __shared__ uint16_t lbkt[CHUNK];                    // 4 KB
  __shared__ uint32_t hist[NB], scn[NB], lofs[NB], base[NB];
  __shared__ uint32_t hs[256];
  const int tid = threadIdx.x;
  const int cb = blockIdx.x * CHUNK;
  const int cnt = min(CHUNK, TOT_E - cb);

  if (tid < NB) hist[tid] = 0;
  __syncthreads();

  uint64_t pay[8];
  uint16_t bk[8];
#pragma unroll
  for (int c = 0; c < 8; ++c) {
    int p = tid + c * 256;
    bk[c] = 0xffffu;
    if (p < cnt) {
      int e = cb + p;
      int a = e / E_EDGES;
      uint32_t r   = (uint32_t)rows[e];
      uint32_t col = (uint32_t)cols[e];
      float    v   = vals[e];
      uint16_t b = (uint16_t)(a * CB + (r >> 10));
      pay[c] = ((uint64_t)__float_as_uint(v) << 32) | ((r & 1023u) << 16) | col;
      bk[c]  = b;
      atomicAdd(&hist[b], 1u);
    }
  }
  __syncthreads();

  // exclusive scan of hist via 256-wide Hillis-Steele
  uint32_t hv = (tid < NB) ? hist[tid] : 0u;
  hs[tid] = hv;
  __syncthreads();
  for (int off = 1; off < 256; off <<= 1) {
    uint32_t v = (tid >= off) ? hs[tid - off] : 0u;
    __syncthreads();
    hs[tid] += v;
    __syncthreads();
  }
  if (tid < NB) {
    uint32_t excl = hs[tid] - hv;
    scn[tid]  = excl;
    lofs[tid] = excl;
    base[tid] = hv ? atomicAdd(&gcur[tid], hv) : 0u;  // global run reservation
  }
  __syncthreads();

  // place into LDS in bin order
#pragma unroll
  for (int c = 0; c < 8; ++c) {
    if (bk[c] != 0xffffu) {
      uint32_t p = atomicAdd(&lofs[bk[c]], 1u);
      lbuf[p] = pay[c];
      lbkt[p] = bk[c];
    }
  }
  __syncthreads();

  // coalesced write-out: gpos = base[k] + (p - scn[k])
#pragma unroll
  for (int c = 0; c < 8; ++c) {
    int p = tid + c * 256;
    if (p < cnt) {
      uint16_t k = lbkt[p];
      sedgeA[base[k] + ((uint32_t)p - scn[k])] = lbuf[p];
    }
  }
}

// ---------------- pass 2: within each coarse bin, exact row sort + offs ----------------
// Destination span per block ~131 KB -> L2-resident -> writes merge.
__global__ __launch_bounds__(256) void k_pass2(const uint32_t* __restrict__ gbase,
                                               const uint64_t* __restrict__ sedgeA,
                                               uint64_t* __restrict__ sedgeB,
                                               uint32_t* __restrict__ offs) {
  __shared__ uint32_t rh[1024], rs[1024];
  __shared__ uint32_t wsum[256];
  const int tid = threadIdx.x;
  const int b = blockIdx.x;                 // 0..NB-1
  const int a = b / CB, rb = (b % CB) * 1024;
  const int nrows = min(1024, N_NODES - rb);
  const uint32_t s0 = gbase[b], e0 = gbase[b + 1];

#pragma unroll
  for (int c = 0; c < 4; ++c) rh[tid + c * 256] = 0;
  __syncthreads();
  for (uint32_t i = s0 + tid; i < e0; i += 256) {
    uint32_t rl = ((uint32_t)(sedgeA[i] >> 16)) & 1023u;
    atomicAdd(&rh[rl], 1u);
  }
  __syncthreads();

  // scan 1024 = per-thread sum of 4 contiguous + 256-wide scan + local prefix
  uint32_t c0 = rh[tid * 4], c1 = rh[tid * 4 + 1], c2 = rh[tid * 4 + 2], c3 = rh[tid * 4 + 3];
  uint32_t tsum = c0 + c1 + c2 + c3;
  wsum[tid] = tsum;
  __syncthreads();
  for (int off = 1; off < 256; off <<= 1) {
    uint32_t v = (tid >= off) ? wsum[tid - off] : 0u;
    __syncthreads();
    wsum[tid] += v;
    __syncthreads();
  }
  uint32_t run = wsum[tid] - tsum;
  rs[tid * 4] = run;     run += c0;
  rs[tid * 4 + 1] = run; run += c1;
  rs[tid * 4 + 2] = run; run += c2;
  rs[tid * 4 + 3] = run;
  __syncthreads();

  // per-row offs + reset cursors
  for (int r = tid; r < 1024; r += 256) {
    if (r < nrows) offs[(size_t)a * N_NODES + rb + r] = s0 + rs[r];
    rh[r] = rs[r];
  }
  __syncthreads();

  // exact scatter within the bin's 131KB span
  for (uint32_t i = s0 + tid; i < e0; i += 256) {
    uint64_t ed = sedgeA[i];
    uint32_t rl = ((uint32_t)(ed >> 16)) & 1023u;
    uint32_t p = atomicAdd(&rh[rl], 1u);
    sedgeB[s0 + p] = ed;
  }
}

// ---------------- SpMM over CSR: one wave per (a,row), 4-deep unroll ----------------
__global__ void k_spmm_csr(const uint32_t* __restrict__ offs,
                           const uint64_t* __restrict__ sedge,
                           const uint16_t* __restrict__ hp0,
                           float* __restrict__ stack) {
  int gw = (int)((blockIdx.x * (size_t)blockDim.x + threadIdx.x) >> 6);  // (a*N+row)
  int l = threadIdx.x & 63;
  if (gw >= TOT_ROWS) return;
  uint32_t s = offs[gw], e = offs[gw + 1];
  float a0 = 0.0f, a1 = 0.0f;
  const uint32_t* hp32 = (const uint32_t*)hp0;
  uint32_t i = s;
  for (; i + 4 <= e; i += 4) {
    uint64_t e0 = sedge[i], e1 = sedge[i + 1], e2 = sedge[i + 2], e3 = sedge[i + 3];
    uint32_t p0 = hp32[(size_t)((uint32_t)e0 & 0xffffu) * 64 + l];
    uint32_t p1 = hp32[(size_t)((uint32_t)e1 & 0xffffu) * 64 + l];
    uint32_t p2 = hp32[(size_t)((uint32_t)e2 & 0xffffu) * 64 + l];
    uint32_t p3 = hp32[(size_t)((uint32_t)e3 & 0xffffu) * 64 + l];
    float v0 = __uint_as_float((uint32_t)(e0 >> 32));
    float v1 = __uint_as_float((uint32_t)(e1 >> 32));
    float v2 = __uint_as_float((uint32_t)(e2 >> 32));
    float v3 = __uint_as_float((uint32_t)(e3 >> 32));
    a0 += bf2f((uint16_t)(p0 & 0xffffu)) * v0;  a1 += bf2f((uint16_t)(p0 >> 16)) * v0;
    a0 += bf2f((uint16_t)(p1 & 0xffffu)) * v1;  a1 += bf2f((uint16_t)(p1 >> 16)) * v1;
    a0 += bf2f((uint16_t)(p2 & 0xffffu)) * v2;  a1 += bf2f((uint16_t)(p2 >> 16)) * v2;
    a0 += bf2f((uint16_t)(p3 & 0xffffu)) * v3;  a1 += bf2f((uint16_t)(p3 >> 16)) * v3;
  }
  for (; i < e; ++i) {
    uint64_t e0 = sedge[i];
    uint32_t p0 = hp32[(size_t)((uint32_t)e0 & 0xffffu) * 64 + l];
    float v0 = __uint_as_float((uint32_t)(e0 >> 32));
    a0 += bf2f((uint16_t)(p0 & 0xffffu)) * v0;
    a1 += bf2f((uint16_t)(p0 >> 16)) * v0;
  }
  ((float2*)stack)[(size_t)gw * 64 + l] = make_float2(a0, a1);
}

// ---------------- fusion: mean over A ----------------
__global__ void k_fusion(const float* __restrict__ stack, float* __restrict__ fus) {
  const int Q = (N_NODES * DDIM) / 4;
  int t = blockIdx.x * blockDim.x + threadIdx.x;
  if (t >= Q) return;
  const float4* s = (const float4*)stack;
  float4 s0 = s[t], s1 = s[t + Q], s2 = s[t + 2 * Q];
  float4 r;
  r.x = (s0.x + s1.x + s2.x) * (1.0f / 3.0f);
  r.y = (s0.y + s1.y + s2.y) * (1.0f / 3.0f);
  r.z = (s0.z + s1.z + s2.z) * (1.0f / 3.0f);
  r.w = (s0.w + s1.w + s2.w) * (1.0f / 3.0f);
  ((float4*)fus)[t] = r;
}

extern "C" void kernel_launch(void* const* d_in, const int* in_sizes, int n_in,
                              void* d_out, int out_size, void* d_ws, size_t ws_size,
                              hipStream_t stream) {
  const float* seq  = (const float*)d_in[0];
  const float* W1   = (const float*)d_in[1];
  const float* b1   = (const float*)d_in[2];
  const float* W2   = (const float*)d_in[3];
  const float* b2   = (const float*)d_in[4];
  const float* vals = (const float*)d_in[5];
  const int*   rows = (const int*)d_in[6];
  const int*   cols = (const int*)d_in[7];

  float* out       = (float*)d_out;
  float* out_ha    = out;                                       // [N, D]
  float* out_stack = out + (size_t)N_NODES * DDIM;              // [A, N, D]
  float* out_fus   = out_stack + (size_t)A_ADJ * N_NODES * DDIM;

  uint16_t* x   = (uint16_t*)d_ws;                              // [M_PAD, NIN] bf16 (51.2MB)
  uint16_t* h   = x   + (size_t)M_PAD * NIN;                    // [M_PAD, HDIM] bf16
  uint16_t* w1t = h   + (size_t)M_PAD * HDIM;                   // [HDIM, NIN]  bf16
  uint16_t* w2t = w1t + (size_t)HDIM * NIN;                     // [DDIM, HDIM] bf16
  uint16_t* hp0 = w2t + (size_t)DDIM * HDIM;                    // [N, D] bf16

  // partition buffers alias the x region (x dead after k_gemm<0>)
  char* xbase = (char*)d_ws;
  uint64_t* sedgeA = (uint64_t*)(xbase);                          // 19.2 MB
  uint64_t* sedgeB = (uint64_t*)(xbase + 20000 * 1024);           // 19.2 MB
  uint32_t* gh     = (uint32_t*)(xbase + 40000 * 1024);           // [NB]
  uint32_t* gbase  = (uint32_t*)(xbase + 40004 * 1024);           // [NB+1]
  uint32_t* gcur   = (uint32_t*)(xbase + 40008 * 1024);           // [NB]
  uint32_t* offs   = (uint32_t*)(xbase + 40016 * 1024);           // [TOT_ROWS+1] 600KB

  // JAX partitionable-mode split of key (0,42)
  uint32_t k0a, k0b, k1a, k1b;
  threefry2x32(0u, 42u, 0u, 0u, k0a, k0b);
  threefry2x32(0u, 42u, 0u, 1u, k1a, k1b);

  k_transpose<<<(HDIM * NIN / 2 + 255) / 256, 256, 0, stream>>>(W1, w1t, NIN, HDIM);
  k_transpose<<<(HDIM * DDIM / 2 + 255) / 256, 256, 0, stream>>>(W2, w2t, HDIM, DDIM);

  k_dropin<<<((N_NODES * NIN / 4) + 255) / 256, 256, 0, stream>>>(seq, x, k0a, k0b);

  dim3 g1(HDIM / 128, M_PAD / 128);   // (4, 391)
  k_gemm<0><<<g1, 256, 0, stream>>>(x, w1t, b1, h, nullptr, HDIM, NIN);

  // ---- two-level radix partition (x region now dead) ----
  (void)hipMemsetAsync(gh, 0, NB * sizeof(uint32_t), stream);
  k_bhist<<<NCHB, 256, 0, stream>>>(rows, gh);
  k_bscan<<<1, 256, 0, stream>>>(gh, gbase, gcur, offs);
  k_pass1<<<NCHB, 256, 0, stream>>>(rows, cols, vals, gcur, sedgeA);
  k_pass2<<<NB, 256, 0, stream>>>(gbase, sedgeA, sedgeB, offs);

  dim3 g2(DDIM / 128, M_PAD / 128);   // (1, 391)
  k_gemm<1><<<g2, 256, 0, stream>>>(h, w2t, b2, nullptr, out_ha, DDIM, HDIM);

  k_drop2<<<((N_NODES * DDIM / 4) + 255) / 256, 256, 0, stream>>>(out_ha, hp0, k1a, k1b);

  size_t csr_threads = (size_t)TOT_ROWS * 64;
  k_spmm_csr<<<(unsigned)((csr_threads + 255) / 256), 256, 0, stream>>>(offs, sedgeB, hp0, out_stack);

  k_fusion<<<((N_NODES * DDIM / 4) + 255) / 256, 256, 0, stream>>>(out_stack, out_fus);
}

// Round 7
// 344.346 us; speedup vs baseline: 5.7582x; 1.1127x over previous
//
#include <hip/hip_runtime.h>
#include <stdint.h>

#define N_NODES 50000
#define M_PAD   50048   // 391*128
#define NIN     512
#define HDIM    512
#define DDIM    128
#define A_ADJ   3
#define E_EDGES 800000
#define TOT_E   (A_ADJ * E_EDGES)           // 2,400,000
#define TOT_ROWS (A_ADJ * N_NODES)          // 150,000
#define CB      49                          // coarse bins per adjacency (1024 rows each)
#define NB      (A_ADJ * CB)                // 147
#define CHUNK   2048
#define NCHB    ((TOT_E + CHUNK - 1) / CHUNK)   // 1172

typedef __bf16 bf16x8 __attribute__((ext_vector_type(8)));
typedef float  f32x4  __attribute__((ext_vector_type(4)));
typedef const __attribute__((address_space(1))) void* gas1_t;
typedef __attribute__((address_space(3))) void* las3_t;

// ---------------- JAX threefry2x32 (bit-exact, partitionable mode) ----------------
__host__ __device__ inline void tf_round(uint32_t& x0, uint32_t& x1, int r) {
  x0 += x1; x1 = (x1 << r) | (x1 >> (32 - r)); x1 ^= x0;
}
__host__ __device__ inline void threefry2x32(uint32_t k0, uint32_t k1,
                                             uint32_t x0, uint32_t x1,
                                             uint32_t& o0, uint32_t& o1) {
  uint32_t ks2 = k0 ^ k1 ^ 0x1BD11BDAu;
  x0 += k0; x1 += k1;
  tf_round(x0,x1,13); tf_round(x0,x1,15); tf_round(x0,x1,26); tf_round(x0,x1,6);
  x0 += k1; x1 += ks2 + 1u;
  tf_round(x0,x1,17); tf_round(x0,x1,29); tf_round(x0,x1,16); tf_round(x0,x1,24);
  x0 += ks2; x1 += k0 + 2u;
  tf_round(x0,x1,13); tf_round(x0,x1,15); tf_round(x0,x1,26); tf_round(x0,x1,6);
  x0 += k0; x1 += k1 + 3u;
  tf_round(x0,x1,17); tf_round(x0,x1,29); tf_round(x0,x1,16); tf_round(x0,x1,24);
  x0 += k1; x1 += ks2 + 4u;
  tf_round(x0,x1,13); tf_round(x0,x1,15); tf_round(x0,x1,26); tf_round(x0,x1,6);
  x0 += ks2; x1 += k0 + 5u;
  o0 = x0; o1 = x1;
}

__device__ inline bool keep_bit(uint32_t b) {
  float f = __uint_as_float((b >> 9) | 0x3f800000u) - 1.0f;
  return f < 0.8f;
}
__device__ inline uint16_t f2bf(float f) {           // RNE float->bf16
  uint32_t u = __float_as_uint(f);
  return (uint16_t)((u + 0x7fffu + ((u >> 16) & 1u)) >> 16);
}
__device__ inline float bf2f(uint16_t b) { return __uint_as_float(((uint32_t)b) << 16); }

__device__ inline uint32_t rbits32(uint32_t ka, uint32_t kb, uint32_t i) {
  uint32_t o0, o1;
  threefry2x32(ka, kb, 0u, i, o0, o1);
  return o0 ^ o1;
}

// ---------------- input dropout: seq_a (f32) -> x (bf16) ----------------
__global__ void k_dropin(const float* __restrict__ seq, uint16_t* __restrict__ x,
                         uint32_t ka, uint32_t kb) {
  const int TOT4 = (N_NODES * NIN) / 4;
  int t = blockIdx.x * blockDim.x + threadIdx.x;
  if (t >= TOT4) return;
  int i0 = 4 * t;
  float4 v = ((const float4*)seq)[t];
  float f[4] = {v.x, v.y, v.z, v.w};
  uint16_t r[4];
#pragma unroll
  for (int j = 0; j < 4; ++j) {
    uint32_t bits = rbits32(ka, kb, (uint32_t)(i0 + j));
    r[j] = f2bf(keep_bit(bits) ? f[j] * 1.25f : 0.0f);
  }
  uint2 w;
  w.x = (uint32_t)r[0] | ((uint32_t)r[1] << 16);
  w.y = (uint32_t)r[2] | ((uint32_t)r[3] << 16);
  ((uint2*)x)[t] = w;
}

// ---------------- h_a dropout: h_a (f32, d_out) -> hp0 (bf16) ----------------
__global__ void k_drop2(const float* __restrict__ ha, uint16_t* __restrict__ hp0,
                        uint32_t ka, uint32_t kb) {
  const int TOT4 = (N_NODES * DDIM) / 4;
  int t = blockIdx.x * blockDim.x + threadIdx.x;
  if (t >= TOT4) return;
  int i0 = 4 * t;
  float4 v = ((const float4*)ha)[t];
  float f[4] = {v.x, v.y, v.z, v.w};
  uint16_t r[4];
#pragma unroll
  for (int j = 0; j < 4; ++j) {
    uint32_t bits = rbits32(ka, kb, (uint32_t)(i0 + j));
    r[j] = f2bf(keep_bit(bits) ? f[j] * 1.25f : 0.0f);
  }
  uint2 w;
  w.x = (uint32_t)r[0] | ((uint32_t)r[1] << 16);
  w.y = (uint32_t)r[2] | ((uint32_t)r[3] << 16);
  ((uint2*)hp0)[t] = w;
}

// ---------------- weight transpose + bf16 convert ----------------
__global__ void k_transpose(const float* __restrict__ W, uint16_t* __restrict__ Wt,
                            int R, int C) {
  int t = blockIdx.x * blockDim.x + threadIdx.x;
  if (t >= (R * C) / 2) return;
  int k2 = (2 * t) % R;
  int n  = (2 * t) / R;
  uint32_t p = (uint32_t)f2bf(W[(size_t)k2 * C + n])
             | ((uint32_t)f2bf(W[(size_t)(k2 + 1) * C + n]) << 16);
  *(uint32_t*)&Wt[(size_t)n * R + k2] = p;
}

// ---------------- GEMM with global_load_lds (width=16) staging ----------------
template <int MODE>
__global__ __launch_bounds__(256) void k_gemm(const uint16_t* __restrict__ A,
                                              const uint16_t* __restrict__ Bt,
                                              const float* __restrict__ bias,
                                              uint16_t* __restrict__ hOut,
                                              float* __restrict__ fOut,
                                              int Nn, int K) {
  __shared__ __align__(16) uint16_t As[128 * 32];
  __shared__ __align__(16) uint16_t Bs[128 * 32];
  const int t  = threadIdx.x;
  const int w  = t >> 6, l = t & 63;
  const int lm = l & 15, kg = l >> 4;
  const int wr = w >> 1, wc = w & 1;
  const int rowbase = blockIdx.y * 128;
  const int colbase = blockIdx.x * 128;
  const int c0 = t, c1 = t + 256;

  f32x4 acc[4][4] = {};

  for (int kt = 0; kt < K; kt += 32) {
    __syncthreads();                                  // previous compute done
    __builtin_amdgcn_global_load_lds(
        (gas1_t)&A [(size_t)(rowbase + (c0 >> 2)) * K + kt + (c0 & 3) * 8],
        (las3_t)&As[c0 * 8], 16, 0, 0);
    __builtin_amdgcn_global_load_lds(
        (gas1_t)&A [(size_t)(rowbase + (c1 >> 2)) * K + kt + (c1 & 3) * 8],
        (las3_t)&As[c1 * 8], 16, 0, 0);
    __builtin_amdgcn_global_load_lds(
        (gas1_t)&Bt[(size_t)(colbase + (c0 >> 2)) * K + kt + (c0 & 3) * 8],
        (las3_t)&Bs[c0 * 8], 16, 0, 0);
    __builtin_amdgcn_global_load_lds(
        (gas1_t)&Bt[(size_t)(colbase + (c1 >> 2)) * K + kt + (c1 & 3) * 8],
        (las3_t)&Bs[c1 * 8], 16, 0, 0);
    __syncthreads();                                  // vmcnt(0) drained, tile ready

    bf16x8 af[4], bfr[4];
#pragma unroll
    for (int m = 0; m < 4; ++m)
      af[m] = *(const bf16x8*)&As[(wr * 64 + m * 16 + lm) * 32 + kg * 8];
#pragma unroll
    for (int n = 0; n < 4; ++n)
      bfr[n] = *(const bf16x8*)&Bs[(wc * 64 + n * 16 + lm) * 32 + kg * 8];
#pragma unroll
    for (int m = 0; m < 4; ++m)
#pragma unroll
      for (int n = 0; n < 4; ++n)
        acc[m][n] = __builtin_amdgcn_mfma_f32_16x16x32_bf16(af[m], bfr[n], acc[m][n], 0, 0, 0);
  }

#pragma unroll
  for (int m = 0; m < 4; ++m) {
    int r0 = rowbase + wr * 64 + m * 16 + kg * 4;
#pragma unroll
    for (int n = 0; n < 4; ++n) {
      int cc = colbase + wc * 64 + n * 16 + lm;
      float bv = bias[cc];
#pragma unroll
      for (int r = 0; r < 4; ++r) {
        int row = r0 + r;
        if (row < N_NODES) {
          float v = acc[m][n][r] + bv;
          if (MODE == 0) hOut[(size_t)row * Nn + cc] = f2bf(fmaxf(v, 0.0f));
          else           fOut[(size_t)row * Nn + cc] = v;
        }
      }
    }
  }
}

// ---------------- coarse histogram: 147 bins, LDS-staged ----------------
__global__ __launch_bounds__(256) void k_bhist(const int* __restrict__ rows,
                                               uint32_t* __restrict__ gh) {
  __shared__ uint32_t h[NB];
  const int tid = threadIdx.x;
  if (tid < NB) h[tid] = 0;
  __syncthreads();
  const int cb = blockIdx.x * CHUNK;
  const int cnt = min(CHUNK, TOT_E - cb);
  for (int c = tid; c < cnt; c += 256) {
    int e = cb + c;
    int a = e / E_EDGES;
    uint32_t r = (uint32_t)rows[e];
    atomicAdd(&h[a * CB + (r >> 10)], 1u);
  }
  __syncthreads();
  if (tid < NB && h[tid]) atomicAdd(&gh[tid], h[tid]);
}

// ---------------- coarse scan: 147 bins -> bases & cursors ----------------
__global__ __launch_bounds__(256) void k_bscan(const uint32_t* __restrict__ gh,
                                               uint32_t* __restrict__ gbase,
                                               uint32_t* __restrict__ gcur,
                                               uint32_t* __restrict__ offs) {
  __shared__ uint32_t s[256];
  const int tid = threadIdx.x;
  uint32_t v = (tid < NB) ? gh[tid] : 0u;
  s[tid] = v;
  __syncthreads();
  for (int off = 1; off < 256; off <<= 1) {
    uint32_t w = (tid >= off) ? s[tid - off] : 0u;
    __syncthreads();
    s[tid] += w;
    __syncthreads();
  }
  if (tid < NB) { uint32_t excl = s[tid] - v; gbase[tid] = excl; gcur[tid] = excl; }
  if (tid == NB - 1) gbase[NB] = s[tid];
  if (tid == 0) offs[TOT_ROWS] = (uint32_t)TOT_E;
}

// ---------------- pass 1: chunk-sort 2048 edges into coarse-bin runs ----------------
__global__ __launch_bounds__(256) void k_pass1(const int* __restrict__ rows,
                                               const int* __restrict__ cols,
                                               const float* __restrict__ vals,
                                               uint32_t* __restrict__ gcur,
                                               uint64_t* __restrict__ sedgeA) {
  __shared__ __align__(16) uint64_t lbuf[CHUNK];      // 16 KB
  __shared__ uint16_t lbkt[CHUNK];                    // 4 KB
  __shared__ uint32_t hist[NB], scn[NB], lofs[NB], base[NB];
  __shared__ uint32_t hs[256];
  const int tid = threadIdx.x;
  const int cb = blockIdx.x * CHUNK;
  const int cnt = min(CHUNK, TOT_E - cb);

  if (tid < NB) hist[tid] = 0;
  __syncthreads();

  uint64_t pay[8];
  uint16_t bk[8];
#pragma unroll
  for (int c = 0; c < 8; ++c) {
    int p = tid + c * 256;
    bk[c] = 0xffffu;
    if (p < cnt) {
      int e = cb + p;
      int a = e / E_EDGES;
      uint32_t r   = (uint32_t)rows[e];
      uint32_t col = (uint32_t)cols[e];
      float    v   = vals[e];
      uint16_t b = (uint16_t)(a * CB + (r >> 10));
      pay[c] = ((uint64_t)__float_as_uint(v) << 32) | ((r & 1023u) << 16) | col;
      bk[c]  = b;
      atomicAdd(&hist[b], 1u);
    }
  }
  __syncthreads();

  uint32_t hv = (tid < NB) ? hist[tid] : 0u;
  hs[tid] = hv;
  __syncthreads();
  for (int off = 1; off < 256; off <<= 1) {
    uint32_t v = (tid >= off) ? hs[tid - off] : 0u;
    __syncthreads();
    hs[tid] += v;
    __syncthreads();
  }
  if (tid < NB) {
    uint32_t excl = hs[tid] - hv;
    scn[tid]  = excl;
    lofs[tid] = excl;
    base[tid] = hv ? atomicAdd(&gcur[tid], hv) : 0u;
  }
  __syncthreads();

#pragma unroll
  for (int c = 0; c < 8; ++c) {
    if (bk[c] != 0xffffu) {
      uint32_t p = atomicAdd(&lofs[bk[c]], 1u);
      lbuf[p] = pay[c];
      lbkt[p] = bk[c];
    }
  }
  __syncthreads();

#pragma unroll
  for (int c = 0; c < 8; ++c) {
    int p = tid + c * 256;
    if (p < cnt) {
      uint16_t k = lbkt[p];
      sedgeA[base[k] + ((uint32_t)p - scn[k])] = lbuf[p];
    }
  }
}

// ---------------- pass 2: within each coarse bin, exact row sort + offs ----------------
__global__ __launch_bounds__(256) void k_pass2(const uint32_t* __restrict__ gbase,
                                               const uint64_t* __restrict__ sedgeA,
                                               uint64_t* __restrict__ sedgeB,
                                               uint32_t* __restrict__ offs) {
  __shared__ uint32_t rh[1024], rs[1024];
  __shared__ uint32_t wsum[256];
  const int tid = threadIdx.x;
  const int b = blockIdx.x;                 // 0..NB-1
  const int a = b / CB, rb = (b % CB) * 1024;
  const int nrows = min(1024, N_NODES - rb);
  const uint32_t s0 = gbase[b], e0 = gbase[b + 1];

#pragma unroll
  for (int c = 0; c < 4; ++c) rh[tid + c * 256] = 0;
  __syncthreads();
  for (uint32_t i = s0 + tid; i < e0; i += 256) {
    uint32_t rl = ((uint32_t)(sedgeA[i] >> 16)) & 1023u;
    atomicAdd(&rh[rl], 1u);
  }
  __syncthreads();

  uint32_t c0 = rh[tid * 4], c1 = rh[tid * 4 + 1], c2 = rh[tid * 4 + 2], c3 = rh[tid * 4 + 3];
  uint32_t tsum = c0 + c1 + c2 + c3;
  wsum[tid] = tsum;
  __syncthreads();
  for (int off = 1; off < 256; off <<= 1) {
    uint32_t v = (tid >= off) ? wsum[tid - off] : 0u;
    __syncthreads();
    wsum[tid] += v;
    __syncthreads();
  }
  uint32_t run = wsum[tid] - tsum;
  rs[tid * 4] = run;     run += c0;
  rs[tid * 4 + 1] = run; run += c1;
  rs[tid * 4 + 2] = run; run += c2;
  rs[tid * 4 + 3] = run;
  __syncthreads();

  for (int r = tid; r < 1024; r += 256) {
    if (r < nrows) offs[(size_t)a * N_NODES + rb + r] = s0 + rs[r];
    rh[r] = rs[r];
  }
  __syncthreads();

  for (uint32_t i = s0 + tid; i < e0; i += 256) {
    uint64_t ed = sedgeA[i];
    uint32_t rl = ((uint32_t)(ed >> 16)) & 1023u;
    uint32_t p = atomicAdd(&rh[rl], 1u);
    sedgeB[s0 + p] = ed;
  }
}

// ---------------- SpMM+fusion: one wave per row, all 3 adjacencies ----------------
// 16 lanes x uint4 per edge, 4 edges per iteration, 2-deep unroll (8 in flight).
__global__ __launch_bounds__(256) void k_spmm_csr3(const uint32_t* __restrict__ offs,
                                                   const uint64_t* __restrict__ sedge,
                                                   const uint16_t* __restrict__ hp0,
                                                   float* __restrict__ stack,
                                                   float* __restrict__ fus) {
  int row = (int)((blockIdx.x * (size_t)blockDim.x + threadIdx.x) >> 6);
  int l = threadIdx.x & 63;
  if (row >= N_NODES) return;
  const int q = l & 15, g = l >> 4;
  const uint4* hp4 = (const uint4*)hp0;
  float fs[8] = {};

#pragma unroll
  for (int a = 0; a < A_ADJ; ++a) {
    uint32_t s = offs[(size_t)a * N_NODES + row];
    uint32_t e = offs[(size_t)a * N_NODES + row + 1];   // contiguous across bins/adjacencies
    float acc[8] = {};
    for (uint32_t i = s; i < e; i += 8) {
      uint32_t i0 = i + g, i1 = i + 4 + g;
      float v0 = 0.f, v1 = 0.f;
      uint32_t col0 = 0, col1 = 0;
      if (i0 < e) { uint64_t ed = sedge[i0]; col0 = (uint32_t)ed & 0xffffu;
                    v0 = __uint_as_float((uint32_t)(ed >> 32)); }
      if (i1 < e) { uint64_t ed = sedge[i1]; col1 = (uint32_t)ed & 0xffffu;
                    v1 = __uint_as_float((uint32_t)(ed >> 32)); }
      uint4 p0 = hp4[(size_t)col0 * 16 + q];
      uint4 p1 = hp4[(size_t)col1 * 16 + q];
      acc[0] += bf2f((uint16_t)(p0.x & 0xffffu)) * v0;  acc[1] += bf2f((uint16_t)(p0.x >> 16)) * v0;
      acc[2] += bf2f((uint16_t)(p0.y & 0xffffu)) * v0;  acc[3] += bf2f((uint16_t)(p0.y >> 16)) * v0;
      acc[4] += bf2f((uint16_t)(p0.z & 0xffffu)) * v0;  acc[5] += bf2f((uint16_t)(p0.z >> 16)) * v0;
      acc[6] += bf2f((uint16_t)(p0.w & 0xffffu)) * v0;  acc[7] += bf2f((uint16_t)(p0.w >> 16)) * v0;
      acc[0] += bf2f((uint16_t)(p1.x & 0xffffu)) * v1;  acc[1] += bf2f((uint16_t)(p1.x >> 16)) * v1;
      acc[2] += bf2f((uint16_t)(p1.y & 0xffffu)) * v1;  acc[3] += bf2f((uint16_t)(p1.y >> 16)) * v1;
      acc[4] += bf2f((uint16_t)(p1.z & 0xffffu)) * v1;  acc[5] += bf2f((uint16_t)(p1.z >> 16)) * v1;
      acc[6] += bf2f((uint16_t)(p1.w & 0xffffu)) * v1;  acc[7] += bf2f((uint16_t)(p1.w >> 16)) * v1;
    }
#pragma unroll
    for (int d = 0; d < 8; ++d) {
      acc[d] += __shfl_xor(acc[d], 16);
      acc[d] += __shfl_xor(acc[d], 32);
    }
    if (l < 16) {
      size_t b4 = ((size_t)a * N_NODES + row) * 32 + (size_t)q * 2;
      ((float4*)stack)[b4]     = make_float4(acc[0], acc[1], acc[2], acc[3]);
      ((float4*)stack)[b4 + 1] = make_float4(acc[4], acc[5], acc[6], acc[7]);
    }
#pragma unroll
    for (int d = 0; d < 8; ++d) fs[d] += acc[d];
  }
  if (l < 16) {
    const float k3 = 1.0f / 3.0f;
    size_t b4 = (size_t)row * 32 + (size_t)q * 2;
    ((float4*)fus)[b4]     = make_float4(fs[0] * k3, fs[1] * k3, fs[2] * k3, fs[3] * k3);
    ((float4*)fus)[b4 + 1] = make_float4(fs[4] * k3, fs[5] * k3, fs[6] * k3, fs[7] * k3);
  }
}

extern "C" void kernel_launch(void* const* d_in, const int* in_sizes, int n_in,
                              void* d_out, int out_size, void* d_ws, size_t ws_size,
                              hipStream_t stream) {
  const float* seq  = (const float*)d_in[0];
  const float* W1   = (const float*)d_in[1];
  const float* b1   = (const float*)d_in[2];
  const float* W2   = (const float*)d_in[3];
  const float* b2   = (const float*)d_in[4];
  const float* vals = (const float*)d_in[5];
  const int*   rows = (const int*)d_in[6];
  const int*   cols = (const int*)d_in[7];

  float* out       = (float*)d_out;
  float* out_ha    = out;                                       // [N, D]
  float* out_stack = out + (size_t)N_NODES * DDIM;              // [A, N, D]
  float* out_fus   = out_stack + (size_t)A_ADJ * N_NODES * DDIM;

  uint16_t* x   = (uint16_t*)d_ws;                              // [M_PAD, NIN] bf16 (51.2MB)
  uint16_t* h   = x   + (size_t)M_PAD * NIN;                    // [M_PAD, HDIM] bf16
  uint16_t* w1t = h   + (size_t)M_PAD * HDIM;                   // [HDIM, NIN]  bf16
  uint16_t* w2t = w1t + (size_t)HDIM * NIN;                     // [DDIM, HDIM] bf16
  uint16_t* hp0 = w2t + (size_t)DDIM * HDIM;                    // [N, D] bf16

  // partition buffers alias the x region (x dead after k_gemm<0>)
  char* xbase = (char*)d_ws;
  uint64_t* sedgeA = (uint64_t*)(xbase);                          // 19.2 MB
  uint64_t* sedgeB = (uint64_t*)(xbase + 20000 * 1024);           // 19.2 MB
  uint32_t* gh     = (uint32_t*)(xbase + 40000 * 1024);           // [NB]
  uint32_t* gbase  = (uint32_t*)(xbase + 40004 * 1024);           // [NB+1]
  uint32_t* gcur   = (uint32_t*)(xbase + 40008 * 1024);           // [NB]
  uint32_t* offs   = (uint32_t*)(xbase + 40016 * 1024);           // [TOT_ROWS+1] 600KB

  // JAX partitionable-mode split of key (0,42)
  uint32_t k0a, k0b, k1a, k1b;
  threefry2x32(0u, 42u, 0u, 0u, k0a, k0b);
  threefry2x32(0u, 42u, 0u, 1u, k1a, k1b);

  k_transpose<<<(HDIM * NIN / 2 + 255) / 256, 256, 0, stream>>>(W1, w1t, NIN, HDIM);
  k_transpose<<<(HDIM * DDIM / 2 + 255) / 256, 256, 0, stream>>>(W2, w2t, HDIM, DDIM);

  k_dropin<<<((N_NODES * NIN / 4) + 255) / 256, 256, 0, stream>>>(seq, x, k0a, k0b);

  dim3 g1(HDIM / 128, M_PAD / 128);   // (4, 391)
  k_gemm<0><<<g1, 256, 0, stream>>>(x, w1t, b1, h, nullptr, HDIM, NIN);

  // ---- two-level radix partition (x region now dead) ----
  (void)hipMemsetAsync(gh, 0, NB * sizeof(uint32_t), stream);
  k_bhist<<<NCHB, 256, 0, stream>>>(rows, gh);
  k_bscan<<<1, 256, 0, stream>>>(gh, gbase, gcur, offs);
  k_pass1<<<NCHB, 256, 0, stream>>>(rows, cols, vals, gcur, sedgeA);
  k_pass2<<<NB, 256, 0, stream>>>(gbase, sedgeA, sedgeB, offs);

  dim3 g2(DDIM / 128, M_PAD / 128);   // (1, 391)
  k_gemm<1><<<g2, 256, 0, stream>>>(h, w2t, b2, nullptr, out_ha, DDIM, HDIM);

  k_drop2<<<((N_NODES * DDIM / 4) + 255) / 256, 256, 0, stream>>>(out_ha, hp0, k1a, k1b);

  // one wave per row (all 3 adjacencies + fused mean)
  k_spmm_csr3<<<(N_NODES * 64 + 255) / 256, 256, 0, stream>>>(offs, sedgeB, hp0, out_stack, out_fus);
}